// Round 2
// baseline (4844.644 us; speedup 1.0000x reference)
//
#include <hip/hip_runtime.h>

#define TOKENS 8192
#define INPUT  1024
#define HIDDEN 16384
#define KSEL   32
#define NCAND  48

// ---------------- Encode GEMM: pre = (x - peb) @ WT + b1 ----------------
// C[M=chunk, N=16384] fp32. 128x128 tile, BK=16, 256 threads, 8x8 per thread.
#define BM 128
#define BN 128
#define BK 16

__global__ __launch_bounds__(256) void gemm_enc(
    const float* __restrict__ x,     // [TOKENS, INPUT]
    const float* __restrict__ peb,   // [INPUT]
    const float* __restrict__ WT,    // [INPUT, HIDDEN]
    const float* __restrict__ bias1, // [HIDDEN]
    float* __restrict__ pre,         // [chunkM, HIDDEN] (chunk-local rows)
    int tok0)
{
    __shared__ float As[BK][BM + 4];
    __shared__ float Bs[BK][BN];

    const int tid = threadIdx.x;
    const int bm = blockIdx.y, bn = blockIdx.x;
    const int row0 = tok0 + bm * BM;

    float4 aReg[2], bReg[2];

    auto loadA = [&](int kt) {
#pragma unroll
        for (int i = 0; i < 2; ++i) {
            int idx = i * 256 + tid;
            int r_ = idx >> 2, c4 = idx & 3;
            aReg[i] = *(const float4*)&x[(size_t)(row0 + r_) * INPUT + kt * BK + c4 * 4];
        }
    };
    auto loadB = [&](int kt) {
#pragma unroll
        for (int i = 0; i < 2; ++i) {
            int idx = i * 256 + tid;
            int r_ = idx >> 5, c4 = idx & 31;
            bReg[i] = *(const float4*)&WT[(size_t)(kt * BK + r_) * HIDDEN + bn * BN + c4 * 4];
        }
    };
    auto storeTiles = [&](int kt) {
#pragma unroll
        for (int i = 0; i < 2; ++i) {
            int idx = i * 256 + tid;
            int r_ = idx >> 2, c4 = idx & 3;
            const float4 pb = *(const float4*)&peb[kt * BK + c4 * 4];
            As[c4 * 4 + 0][r_] = aReg[i].x - pb.x;
            As[c4 * 4 + 1][r_] = aReg[i].y - pb.y;
            As[c4 * 4 + 2][r_] = aReg[i].z - pb.z;
            As[c4 * 4 + 3][r_] = aReg[i].w - pb.w;
            int br = idx >> 5, bc4 = idx & 31;
            *(float4*)&Bs[br][bc4 * 4] = bReg[i];
        }
    };

    float acc[8][8];
#pragma unroll
    for (int i = 0; i < 8; ++i)
#pragma unroll
        for (int j = 0; j < 8; ++j) acc[i][j] = 0.f;

    const int tr = tid >> 4, tc = tid & 15;
    const int NK = INPUT / BK; // 64

    loadA(0); loadB(0);
    for (int kt = 0; kt < NK; ++kt) {
        __syncthreads();
        storeTiles(kt);
        __syncthreads();
        if (kt + 1 < NK) { loadA(kt + 1); loadB(kt + 1); }
#pragma unroll
        for (int kk = 0; kk < BK; ++kk) {
            float4 a0 = *(const float4*)&As[kk][tr * 8];
            float4 a1 = *(const float4*)&As[kk][tr * 8 + 4];
            float4 b0 = *(const float4*)&Bs[kk][tc * 8];
            float4 b1v = *(const float4*)&Bs[kk][tc * 8 + 4];
            float a[8] = {a0.x, a0.y, a0.z, a0.w, a1.x, a1.y, a1.z, a1.w};
            float b[8] = {b0.x, b0.y, b0.z, b0.w, b1v.x, b1v.y, b1v.z, b1v.w};
#pragma unroll
            for (int i = 0; i < 8; ++i)
#pragma unroll
                for (int j = 0; j < 8; ++j) acc[i][j] = fmaf(a[i], b[j], acc[i][j]);
        }
    }

    const int ncol = bn * BN + tc * 8;
    const float4 bb0 = *(const float4*)&bias1[ncol];
    const float4 bb1 = *(const float4*)&bias1[ncol + 4];
#pragma unroll
    for (int i = 0; i < 8; ++i) {
        int m = bm * BM + tr * 8 + i;
        float4 o0 = {acc[i][0] + bb0.x, acc[i][1] + bb0.y, acc[i][2] + bb0.z, acc[i][3] + bb0.w};
        float4 o1 = {acc[i][4] + bb1.x, acc[i][5] + bb1.y, acc[i][6] + bb1.z, acc[i][7] + bb1.w};
        *(float4*)&pre[(size_t)m * HIDDEN + ncol] = o0;
        *(float4*)&pre[(size_t)m * HIDDEN + ncol + 4] = o1;
    }
}

// ---------------- Candidate top-NCAND per token (fp32 screen) ----------------
__global__ __launch_bounds__(256) void topcand(
    const float* __restrict__ pre, // [chunkM, HIDDEN]
    int* __restrict__ cand,        // [TOKENS, NCAND]
    int tok0)
{
    const int tid = threadIdx.x;
    const int t = blockIdx.x;
    const float* row = pre + (size_t)t * HIDDEN;

    unsigned ukey[64];
#pragma unroll
    for (int e = 0; e < 64; ++e) {
        unsigned u = __float_as_uint(row[tid + e * 256]);
        ukey[e] = u ^ (((unsigned)((int)u >> 31)) | 0x80000000u);
    }

    unsigned long long dead = 0;
    __shared__ unsigned long long wred[4];
    __shared__ unsigned long long winner;
    const int gtok = tok0 + t;

    auto scan = [&]() {
        unsigned long long best = 0;
#pragma unroll
        for (int e = 0; e < 64; ++e) {
            unsigned long long key =
                ((unsigned long long)ukey[e] << 32) | (unsigned)((0xFFFFFFFFu - e * 256) - tid);
            if (!((dead >> e) & 1ull)) best = (best < key) ? key : best;
        }
        return best;
    };

    unsigned long long mykey = scan();

    for (int it = 0; it < NCAND; ++it) {
        unsigned long long k = mykey;
#pragma unroll
        for (int s = 32; s > 0; s >>= 1) {
            unsigned long long o = __shfl_xor(k, s, 64);
            k = (k < o) ? o : k;
        }
        if ((tid & 63) == 0) wred[tid >> 6] = k;
        __syncthreads();
        if (tid == 0) {
            unsigned long long w = wred[0];
            if (wred[1] > w) w = wred[1];
            if (wred[2] > w) w = wred[2];
            if (wred[3] > w) w = wred[3];
            winner = w;
            cand[(size_t)gtok * NCAND + it] = (int)(0xFFFFFFFFu - (unsigned)w);
        }
        __syncthreads();
        unsigned long long w = winner;
        unsigned gi = 0xFFFFFFFFu - (unsigned)w;
        if ((int)(gi & 255u) == tid) {
            dead |= 1ull << (gi >> 8);
            mykey = scan();
        }
    }
}

// ---------------- Transpose WT -> WTT[HIDDEN][INPUT] ----------------
__global__ __launch_bounds__(256) void transp(
    const float* __restrict__ WT, float* __restrict__ WTT)
{
    __shared__ float tl[64][65];
    const int bx = blockIdx.x; // hidden tile
    const int by = blockIdx.y; // input tile
    const int tid = threadIdx.x;
    const int r0 = tid >> 6;       // 0..3
    const int c = tid & 63;        // 0..63
#pragma unroll
    for (int i = 0; i < 16; ++i) {
        int r = i * 4 + r0;
        tl[r][c] = WT[(size_t)(by * 64 + r) * HIDDEN + bx * 64 + c];
    }
    __syncthreads();
#pragma unroll
    for (int i = 0; i < 16; ++i) {
        int a = i * 4 + r0;
        WTT[(size_t)(bx * 64 + a) * INPUT + by * 64 + c] = tl[c][a];
    }
}

// ---------------- f64 rescore of candidates -> exact top-32 ----------------
__global__ __launch_bounds__(256) void rescore(
    const float* __restrict__ x, const float* __restrict__ peb,
    const float* __restrict__ WTT, const float* __restrict__ bias1,
    const int* __restrict__ cand,  // [TOKENS, NCAND]
    float* __restrict__ vals,      // [TOKENS, 32]
    int* __restrict__ idxo)        // [TOKENS, 32]
{
    const int t = blockIdx.x;
    const int tid = threadIdx.x;
    __shared__ double xcs[INPUT];
    __shared__ double cval[NCAND];
    __shared__ int cidx[NCAND];

#pragma unroll
    for (int i = 0; i < 4; ++i) {
        int j = tid + i * 256;
        xcs[j] = (double)x[(size_t)t * INPUT + j] - (double)peb[j];
    }
    if (tid < NCAND) cidx[tid] = cand[(size_t)t * NCAND + tid];
    __syncthreads();

    const int wid = tid >> 6, lane = tid & 63;
    for (int j = wid; j < NCAND; j += 4) {
        const int h = cidx[j];
        const float* wrow = WTT + (size_t)h * INPUT;
        double s = 0.0;
#pragma unroll
        for (int st = 0; st < 16; ++st)
            s += (double)wrow[lane + st * 64] * xcs[lane + st * 64];
#pragma unroll
        for (int off = 32; off > 0; off >>= 1)
            s += __shfl_xor(s, off, 64);
        if (lane == 0) cval[j] = s + (double)bias1[h];
    }
    __syncthreads();

    if (tid < NCAND) {
        const double v = cval[tid];
        const int h = cidx[tid];
        int rank = 0;
        for (int j = 0; j < NCAND; ++j) {
            double vj = cval[j];
            if (vj > v || (vj == v && cidx[j] < h)) ++rank;
        }
        if (rank < KSEL) {
            vals[(size_t)t * KSEL + rank] = (float)v;
            idxo[(size_t)t * KSEL + rank] = h;
        }
    }
}

// ---------------- Decode ----------------
__global__ __launch_bounds__(256) void decode32(
    const float* __restrict__ vals, const int* __restrict__ idxo,
    const float* __restrict__ W,   // [HIDDEN, INPUT]
    const float* __restrict__ b2,  // [INPUT]
    float* __restrict__ out)       // [TOKENS, INPUT]
{
    const int t = blockIdx.x;
    const int tid = threadIdx.x;
    __shared__ float sv[KSEL];
    __shared__ int si[KSEL];
    if (tid < KSEL) {
        sv[tid] = vals[(size_t)t * KSEL + tid];
        si[tid] = idxo[(size_t)t * KSEL + tid];
    }
    __syncthreads();
    const int c = tid * 4;
    float4 acc = *(const float4*)&b2[c];
#pragma unroll 8
    for (int j = 0; j < KSEL; ++j) {
        const float4 w = *(const float4*)&W[(size_t)si[j] * INPUT + c];
        const float s = sv[j];
        acc.x += s * w.x; acc.y += s * w.y; acc.z += s * w.z; acc.w += s * w.w;
    }
    *(float4*)&out[(size_t)t * INPUT + c] = acc;
}

extern "C" void kernel_launch(void* const* d_in, const int* in_sizes, int n_in,
                              void* d_out, int out_size, void* d_ws, size_t ws_size,
                              hipStream_t stream) {
    const float* x   = (const float*)d_in[0];
    const float* peb = (const float*)d_in[1];
    const float* W   = (const float*)d_in[2];
    const float* WT  = (const float*)d_in[3];
    const float* b1  = (const float*)d_in[4];
    const float* b2  = (const float*)d_in[5];
    float* out = (float*)d_out;

    // ws layout: vals | idx | cand | WTT | preacts chunk
    char* p = (char*)d_ws;
    float* valsb = (float*)p;                 p += (size_t)TOKENS * KSEL * 4;
    int*   idxb  = (int*)p;                   p += (size_t)TOKENS * KSEL * 4;
    int*   candb = (int*)p;                   p += (size_t)TOKENS * NCAND * 4;
    float* WTT   = (float*)p;                 p += (size_t)HIDDEN * INPUT * 4;
    float* pre   = (float*)p;

    size_t used = (size_t)(p - (char*)d_ws);
    size_t avail = ws_size > used ? ws_size - used : 0;
    long cap = (long)(avail / ((size_t)HIDDEN * 4));
    cap = (cap / BM) * BM;
    if (cap > TOKENS) cap = TOKENS;
    if (cap < BM) cap = BM;

    transp<<<dim3(HIDDEN / 64, INPUT / 64), dim3(256), 0, stream>>>(WT, WTT);

    for (int tok0 = 0; tok0 < TOKENS; tok0 += (int)cap) {
        int M = TOKENS - tok0;
        if (M > cap) M = (int)cap;
        dim3 g(HIDDEN / BN, M / BM);
        gemm_enc<<<g, dim3(256), 0, stream>>>(x, peb, WT, b1, pre, tok0);
        topcand<<<dim3(M), dim3(256), 0, stream>>>(pre, candb, tok0);
    }

    rescore<<<dim3(TOKENS), dim3(256), 0, stream>>>(x, peb, WTT, b1, candb, valsb, idxb);
    decode32<<<dim3(TOKENS), dim3(256), 0, stream>>>(valsb, idxb, W, b2, out);
}

// Round 3
// 1840.961 us; speedup vs baseline: 2.6316x; 2.6316x over previous
//
#include <hip/hip_runtime.h>
#include <hip/hip_bf16.h>

#define TOKENS 8192
#define INPUT  1024
#define HIDDEN 16384
#define KSEL   32
#define NCAND  48
#define BM 128
#define BN 128

typedef __attribute__((ext_vector_type(8))) short bf16x8;
typedef __attribute__((ext_vector_type(4))) float f32x4;

#define GLOAD_LDS16(g, l) __builtin_amdgcn_global_load_lds(              \
    (const __attribute__((address_space(1))) void*)(const void*)(g),     \
    (__attribute__((address_space(3))) void*)(void*)(l), 16, 0, 0)

__device__ inline short f2bf(float f) {
    unsigned u = __float_as_uint(f);
    u += 0x7FFFu + ((u >> 16) & 1u);   // RNE
    return (short)(u >> 16);
}

// ---------------- Abf = bf16(x - peb) ----------------
__global__ __launch_bounds__(256) void conv_x(
    const float* __restrict__ x, const float* __restrict__ peb,
    short* __restrict__ Abf)
{
    const int g = (blockIdx.x * 256 + threadIdx.x) * 8;
    const int col = g & (INPUT - 1);
    float4 v0 = *(const float4*)&x[g];
    float4 v1 = *(const float4*)&x[g + 4];
    float4 p0 = *(const float4*)&peb[col];
    float4 p1 = *(const float4*)&peb[col + 4];
    short o[8] = {f2bf(v0.x - p0.x), f2bf(v0.y - p0.y), f2bf(v0.z - p0.z), f2bf(v0.w - p0.w),
                  f2bf(v1.x - p1.x), f2bf(v1.y - p1.y), f2bf(v1.z - p1.z), f2bf(v1.w - p1.w)};
    *(bf16x8*)&Abf[g] = *(bf16x8*)o;
}

// ---------------- Transpose WT -> WTT[HIDDEN][INPUT] (fp32, for rescore) ----------------
__global__ __launch_bounds__(256) void transp(
    const float* __restrict__ WT, float* __restrict__ WTT)
{
    __shared__ float tl[64][65];
    const int bx = blockIdx.x, by = blockIdx.y;
    const int tid = threadIdx.x;
    const int r0 = tid >> 6, c = tid & 63;
#pragma unroll
    for (int i = 0; i < 16; ++i) {
        int r = i * 4 + r0;
        tl[r][c] = WT[(size_t)(by * 64 + r) * HIDDEN + bx * 64 + c];
    }
    __syncthreads();
#pragma unroll
    for (int i = 0; i < 16; ++i) {
        int a = i * 4 + r0;
        WTT[(size_t)(bx * 64 + a) * INPUT + by * 64 + c] = tl[c][a];
    }
}

// ---------------- Bt = bf16(WTT) elementwise ----------------
__global__ __launch_bounds__(256) void conv_bt(
    const float* __restrict__ WTT, short* __restrict__ Bt)
{
    const int g = (blockIdx.x * 256 + threadIdx.x) * 8;
    float4 v0 = *(const float4*)&WTT[g];
    float4 v1 = *(const float4*)&WTT[g + 4];
    short o[8] = {f2bf(v0.x), f2bf(v0.y), f2bf(v0.z), f2bf(v0.w),
                  f2bf(v1.x), f2bf(v1.y), f2bf(v1.z), f2bf(v1.w)};
    *(bf16x8*)&Bt[g] = *(bf16x8*)o;
}

// ---------------- bf16 MFMA GEMM: pre = Abf @ Bt^T + b1 (m97 structure) ----------------
__global__ __launch_bounds__(256) void gemm_bf16(
    const short* __restrict__ A,   // [TOKENS][INPUT] bf16
    const short* __restrict__ Bt,  // [HIDDEN][INPUT] bf16
    const float* __restrict__ bias1,
    float* __restrict__ pre,       // [chunkM][HIDDEN] fp32
    int tok0)
{
    __shared__ short As[BM * 32];
    __shared__ short Bs[BN * 32];
    const int tid = threadIdx.x;
    const int bn = blockIdx.x, bm = blockIdx.y;
    const int row0 = tok0 + bm * BM;
    const int col0 = bn * BN;
    const int lane = tid & 63, w = tid >> 6;
    const int wr = w >> 1, wc = w & 1;

    f32x4 acc[4][4];
#pragma unroll
    for (int m = 0; m < 4; ++m)
#pragma unroll
        for (int n = 0; n < 4; ++n) acc[m][n] = (f32x4){0.f, 0.f, 0.f, 0.f};

    const int rbase = lane & 15;
    const int koff = (lane >> 4) * 8;

    for (int kt = 0; kt < INPUT / 32; ++kt) {
        __syncthreads();
#pragma unroll
        for (int i = 0; i < 2; ++i) {
            int idx = i * 256 + tid;
            int r = idx >> 2, seg = idx & 3;
            GLOAD_LDS16(&A[(size_t)(row0 + r) * INPUT + kt * 32 + seg * 8], &As[idx * 8]);
            GLOAD_LDS16(&Bt[(size_t)(col0 + r) * INPUT + kt * 32 + seg * 8], &Bs[idx * 8]);
        }
        __syncthreads();

        bf16x8 af[4], bfr[4];
#pragma unroll
        for (int m = 0; m < 4; ++m)
            af[m] = *(const bf16x8*)&As[(wr * 64 + m * 16 + rbase) * 32 + koff];
#pragma unroll
        for (int n = 0; n < 4; ++n)
            bfr[n] = *(const bf16x8*)&Bs[(wc * 64 + n * 16 + rbase) * 32 + koff];
#pragma unroll
        for (int m = 0; m < 4; ++m)
#pragma unroll
            for (int n = 0; n < 4; ++n)
                acc[m][n] = __builtin_amdgcn_mfma_f32_16x16x32_bf16(af[m], bfr[n], acc[m][n], 0, 0, 0);
    }

#pragma unroll
    for (int n = 0; n < 4; ++n) {
        const int col = col0 + wc * 64 + n * 16 + (lane & 15);
        const float bb = bias1[col];
#pragma unroll
        for (int m = 0; m < 4; ++m) {
#pragma unroll
            for (int r = 0; r < 4; ++r) {
                int row = bm * BM + wr * 64 + m * 16 + (lane >> 4) * 4 + r;
                pre[(size_t)row * HIDDEN + col] = acc[m][n][r] + bb;
            }
        }
    }
}

// ---------------- Candidate top-NCAND per token (screen) ----------------
__global__ __launch_bounds__(256) void topcand(
    const float* __restrict__ pre, // [chunkM][HIDDEN]
    int* __restrict__ cand,        // [TOKENS][NCAND]
    int tok0)
{
    const int tid = threadIdx.x;
    const int t = blockIdx.x;
    const float* row = pre + (size_t)t * HIDDEN;

    unsigned ukey[64];
#pragma unroll
    for (int e = 0; e < 64; ++e) {
        unsigned u = __float_as_uint(row[tid + e * 256]);
        ukey[e] = u ^ (((unsigned)((int)u >> 31)) | 0x80000000u);
    }

    unsigned long long dead = 0;
    __shared__ unsigned long long wred[4];
    __shared__ unsigned long long winner;
    const int gtok = tok0 + t;

    auto scan = [&]() {
        unsigned long long best = 0;
#pragma unroll
        for (int e = 0; e < 64; ++e) {
            unsigned long long key =
                ((unsigned long long)ukey[e] << 32) | (unsigned)((0xFFFFFFFFu - e * 256) - tid);
            if (!((dead >> e) & 1ull)) best = (best < key) ? key : best;
        }
        return best;
    };

    unsigned long long mykey = scan();

    for (int it = 0; it < NCAND; ++it) {
        unsigned long long k = mykey;
#pragma unroll
        for (int s = 32; s > 0; s >>= 1) {
            unsigned long long o = __shfl_xor(k, s, 64);
            k = (k < o) ? o : k;
        }
        if ((tid & 63) == 0) wred[tid >> 6] = k;
        __syncthreads();
        if (tid == 0) {
            unsigned long long wv = wred[0];
            if (wred[1] > wv) wv = wred[1];
            if (wred[2] > wv) wv = wred[2];
            if (wred[3] > wv) wv = wred[3];
            winner = wv;
            cand[(size_t)gtok * NCAND + it] = (int)(0xFFFFFFFFu - (unsigned)wv);
        }
        __syncthreads();
        unsigned long long wv = winner;
        unsigned gi = 0xFFFFFFFFu - (unsigned)wv;
        if ((int)(gi & 255u) == tid) {
            dead |= 1ull << (gi >> 8);
            mykey = scan();
        }
    }
}

// ---------------- f64 rescore of candidates -> exact top-32 ----------------
__global__ __launch_bounds__(256) void rescore(
    const float* __restrict__ x, const float* __restrict__ peb,
    const float* __restrict__ WTT, const float* __restrict__ bias1,
    const int* __restrict__ cand,
    float* __restrict__ vals, int* __restrict__ idxo)
{
    const int t = blockIdx.x;
    const int tid = threadIdx.x;
    __shared__ double xcs[INPUT];
    __shared__ double cval[NCAND];
    __shared__ int cidx[NCAND];

#pragma unroll
    for (int i = 0; i < 4; ++i) {
        int j = tid + i * 256;
        xcs[j] = (double)x[(size_t)t * INPUT + j] - (double)peb[j];
    }
    if (tid < NCAND) cidx[tid] = cand[(size_t)t * NCAND + tid];
    __syncthreads();

    const int wid = tid >> 6, lane = tid & 63;
    for (int j = wid; j < NCAND; j += 4) {
        const int h = cidx[j];
        const float* wrow = WTT + (size_t)h * INPUT;
        double s = 0.0;
#pragma unroll
        for (int st = 0; st < 16; ++st)
            s += (double)wrow[lane + st * 64] * xcs[lane + st * 64];
#pragma unroll
        for (int off = 32; off > 0; off >>= 1)
            s += __shfl_xor(s, off, 64);
        if (lane == 0) cval[j] = s + (double)bias1[h];
    }
    __syncthreads();

    if (tid < NCAND) {
        const double v = cval[tid];
        const int h = cidx[tid];
        int rank = 0;
        for (int j = 0; j < NCAND; ++j) {
            double vj = cval[j];
            if (vj > v || (vj == v && cidx[j] < h)) ++rank;
        }
        if (rank < KSEL) {
            vals[(size_t)t * KSEL + rank] = (float)v;
            idxo[(size_t)t * KSEL + rank] = h;
        }
    }
}

// ---------------- Decode ----------------
__global__ __launch_bounds__(256) void decode32(
    const float* __restrict__ vals, const int* __restrict__ idxo,
    const float* __restrict__ W, const float* __restrict__ b2,
    float* __restrict__ out)
{
    const int t = blockIdx.x;
    const int tid = threadIdx.x;
    __shared__ float sv[KSEL];
    __shared__ int si[KSEL];
    if (tid < KSEL) {
        sv[tid] = vals[(size_t)t * KSEL + tid];
        si[tid] = idxo[(size_t)t * KSEL + tid];
    }
    __syncthreads();
    const int c = tid * 4;
    float4 acc = *(const float4*)&b2[c];
#pragma unroll 8
    for (int j = 0; j < KSEL; ++j) {
        const float4 wv = *(const float4*)&W[(size_t)si[j] * INPUT + c];
        const float s = sv[j];
        acc.x += s * wv.x; acc.y += s * wv.y; acc.z += s * wv.z; acc.w += s * wv.w;
    }
    *(float4*)&out[(size_t)t * INPUT + c] = acc;
}

extern "C" void kernel_launch(void* const* d_in, const int* in_sizes, int n_in,
                              void* d_out, int out_size, void* d_ws, size_t ws_size,
                              hipStream_t stream) {
    const float* x   = (const float*)d_in[0];
    const float* peb = (const float*)d_in[1];
    const float* W   = (const float*)d_in[2];
    const float* WT  = (const float*)d_in[3];
    const float* b1  = (const float*)d_in[4];
    const float* b2  = (const float*)d_in[5];
    float* out = (float*)d_out;

    // ws: vals | idx | cand | WTT(f32) | Abf(bf16) | Bt(bf16) | pre chunk (f32)
    char* p = (char*)d_ws;
    float* valsb = (float*)p;  p += (size_t)TOKENS * KSEL * 4;
    int*   idxb  = (int*)p;    p += (size_t)TOKENS * KSEL * 4;
    int*   candb = (int*)p;    p += (size_t)TOKENS * NCAND * 4;
    float* WTT   = (float*)p;  p += (size_t)HIDDEN * INPUT * 4;
    short* Abf   = (short*)p;  p += (size_t)TOKENS * INPUT * 2;
    short* Btb   = (short*)p;  p += (size_t)HIDDEN * INPUT * 2;
    float* pre   = (float*)p;

    size_t used = (size_t)(p - (char*)d_ws);
    size_t avail = ws_size > used ? ws_size - used : 0;
    long cap = (long)(avail / ((size_t)HIDDEN * 4));
    cap = (cap / BM) * BM;
    if (cap > TOKENS) cap = TOKENS;
    if (cap < BM) cap = BM;

    conv_x<<<dim3(TOKENS * INPUT / (256 * 8)), dim3(256), 0, stream>>>(x, peb, Abf);
    transp<<<dim3(HIDDEN / 64, INPUT / 64), dim3(256), 0, stream>>>(WT, WTT);
    conv_bt<<<dim3((size_t)HIDDEN * INPUT / (256 * 8)), dim3(256), 0, stream>>>(WTT, Btb);

    for (int tok0 = 0; tok0 < TOKENS; tok0 += (int)cap) {
        int M = TOKENS - tok0;
        if (M > cap) M = (int)cap;
        gemm_bf16<<<dim3(HIDDEN / BN, M / BM), dim3(256), 0, stream>>>(Abf, Btb, b1, pre, tok0);
        topcand<<<dim3(M), dim3(256), 0, stream>>>(pre, candb, tok0);
    }

    rescore<<<dim3(TOKENS), dim3(256), 0, stream>>>(x, peb, WTT, b1, candb, valsb, idxb);
    decode32<<<dim3(TOKENS), dim3(256), 0, stream>>>(valsb, idxb, W, b2, out);
}

// Round 4
// 957.528 us; speedup vs baseline: 5.0595x; 1.9226x over previous
//
#include <hip/hip_runtime.h>
#include <hip/hip_bf16.h>

#define TOKENS 8192
#define INPUT  1024
#define HIDDEN 16384
#define KSEL   32
#define CANDCAP 96
#define BM 128
#define BN 128

typedef __attribute__((ext_vector_type(8))) short bf16x8;
typedef __attribute__((ext_vector_type(4))) float f32x4;

#define GLOAD_LDS16(g, l) __builtin_amdgcn_global_load_lds(              \
    (const __attribute__((address_space(1))) void*)(const void*)(g),     \
    (__attribute__((address_space(3))) void*)(void*)(l), 16, 0, 0)

__device__ inline short f2bf(float f) {
    unsigned u = __float_as_uint(f);
    u += 0x7FFFu + ((u >> 16) & 1u);   // RNE
    return (short)(u >> 16);
}

// ---------------- Abf = bf16(x - peb) ----------------
__global__ __launch_bounds__(256) void conv_x(
    const float* __restrict__ x, const float* __restrict__ peb,
    short* __restrict__ Abf)
{
    const int g = (blockIdx.x * 256 + threadIdx.x) * 8;
    const int col = g & (INPUT - 1);
    float4 v0 = *(const float4*)&x[g];
    float4 v1 = *(const float4*)&x[g + 4];
    float4 p0 = *(const float4*)&peb[col];
    float4 p1 = *(const float4*)&peb[col + 4];
    short o[8] = {f2bf(v0.x - p0.x), f2bf(v0.y - p0.y), f2bf(v0.z - p0.z), f2bf(v0.w - p0.w),
                  f2bf(v1.x - p1.x), f2bf(v1.y - p1.y), f2bf(v1.z - p1.z), f2bf(v1.w - p1.w)};
    *(bf16x8*)&Abf[g] = *(bf16x8*)o;
}

// ---------------- Transpose WT -> WTT[HIDDEN][INPUT] (fp32, for rescore) ----------------
__global__ __launch_bounds__(256) void transp(
    const float* __restrict__ WT, float* __restrict__ WTT)
{
    __shared__ float tl[64][65];
    const int bx = blockIdx.x, by = blockIdx.y;
    const int tid = threadIdx.x;
    const int r0 = tid >> 6, c = tid & 63;
#pragma unroll
    for (int i = 0; i < 16; ++i) {
        int r = i * 4 + r0;
        tl[r][c] = WT[(size_t)(by * 64 + r) * HIDDEN + bx * 64 + c];
    }
    __syncthreads();
#pragma unroll
    for (int i = 0; i < 16; ++i) {
        int a = i * 4 + r0;
        WTT[(size_t)(bx * 64 + a) * INPUT + by * 64 + c] = tl[c][a];
    }
}

// ---------------- Bt = bf16(WTT) elementwise ----------------
__global__ __launch_bounds__(256) void conv_bt(
    const float* __restrict__ WTT, short* __restrict__ Bt)
{
    const int g = (blockIdx.x * 256 + threadIdx.x) * 8;
    float4 v0 = *(const float4*)&WTT[g];
    float4 v1 = *(const float4*)&WTT[g + 4];
    short o[8] = {f2bf(v0.x), f2bf(v0.y), f2bf(v0.z), f2bf(v0.w),
                  f2bf(v1.x), f2bf(v1.y), f2bf(v1.z), f2bf(v1.w)};
    *(bf16x8*)&Bt[g] = *(bf16x8*)o;
}

// ---------------- bf16 MFMA GEMM: pre_bf16 = bf16(Abf @ Bt^T + b1) ----------------
__global__ __launch_bounds__(256) void gemm_bf16(
    const short* __restrict__ A,   // [TOKENS][INPUT] bf16
    const short* __restrict__ Bt,  // [HIDDEN][INPUT] bf16
    const float* __restrict__ bias1,
    short* __restrict__ pre,       // [chunkM][HIDDEN] bf16
    int tok0)
{
    __shared__ short As[BM * 32];
    __shared__ short Bs[BN * 32];
    const int tid = threadIdx.x;
    const int bn = blockIdx.x, bm = blockIdx.y;
    const int row0 = tok0 + bm * BM;
    const int col0 = bn * BN;
    const int lane = tid & 63, w = tid >> 6;
    const int wr = w >> 1, wc = w & 1;

    f32x4 acc[4][4];
#pragma unroll
    for (int m = 0; m < 4; ++m)
#pragma unroll
        for (int n = 0; n < 4; ++n) acc[m][n] = (f32x4){0.f, 0.f, 0.f, 0.f};

    const int rbase = lane & 15;
    const int koff = (lane >> 4) * 8;

    for (int kt = 0; kt < INPUT / 32; ++kt) {
        __syncthreads();
#pragma unroll
        for (int i = 0; i < 2; ++i) {
            int idx = i * 256 + tid;
            int r = idx >> 2, seg = idx & 3;
            GLOAD_LDS16(&A[(size_t)(row0 + r) * INPUT + kt * 32 + seg * 8], &As[idx * 8]);
            GLOAD_LDS16(&Bt[(size_t)(col0 + r) * INPUT + kt * 32 + seg * 8], &Bs[idx * 8]);
        }
        __syncthreads();

        bf16x8 af[4], bfr[4];
#pragma unroll
        for (int m = 0; m < 4; ++m)
            af[m] = *(const bf16x8*)&As[(wr * 64 + m * 16 + rbase) * 32 + koff];
#pragma unroll
        for (int n = 0; n < 4; ++n)
            bfr[n] = *(const bf16x8*)&Bs[(wc * 64 + n * 16 + rbase) * 32 + koff];
#pragma unroll
        for (int m = 0; m < 4; ++m)
#pragma unroll
            for (int n = 0; n < 4; ++n)
                acc[m][n] = __builtin_amdgcn_mfma_f32_16x16x32_bf16(af[m], bfr[n], acc[m][n], 0, 0, 0);
    }

#pragma unroll
    for (int n = 0; n < 4; ++n) {
        const int col = col0 + wc * 64 + n * 16 + (lane & 15);
        const float bb = bias1[col];
#pragma unroll
        for (int m = 0; m < 4; ++m) {
#pragma unroll
            for (int r = 0; r < 4; ++r) {
                int row = bm * BM + wr * 64 + m * 16 + (lane >> 4) * 4 + r;
                pre[(size_t)row * HIDDEN + col] = f2bf(acc[m][n][r] + bb);
            }
        }
    }
}

// ---------------- Candidate select: all elems >= tau, tau via binary search ----------------
// One block per token. 64 bf16 keys/thread packed 2-per-u32 in registers.
__global__ __launch_bounds__(256) void topcand2(
    const short* __restrict__ pre, // [chunkM][HIDDEN] bf16
    int* __restrict__ cand,        // [TOKENS][CANDCAP]
    int* __restrict__ ncand,       // [TOKENS]
    int tok0)
{
    const int tid = threadIdx.x;
    const int t = blockIdx.x;
    const unsigned short* row = (const unsigned short*)(pre + (size_t)t * HIDDEN);

    unsigned pk[32];
#pragma unroll
    for (int i = 0; i < 8; ++i) {
        uint4 raw = *(const uint4*)&row[(size_t)tid * 64 + i * 8];
        unsigned rr[4] = {raw.x, raw.y, raw.z, raw.w};
#pragma unroll
        for (int j = 0; j < 4; ++j) {
            unsigned lo16 = rr[j] & 0xFFFFu, hi16 = rr[j] >> 16;
            lo16 ^= (((lo16 >> 15) * 0xFFFFu) | 0x8000u);
            hi16 ^= (((hi16 >> 15) * 0xFFFFu) | 0x8000u);
            pk[i * 4 + j] = lo16 | (hi16 << 16);
        }
    }

    __shared__ unsigned wsum[4];
    __shared__ unsigned scount;
    const int lane = tid & 63, wid = tid >> 6;

    auto countGE = [&](unsigned tau) -> unsigned {
        unsigned c = 0;
#pragma unroll
        for (int i = 0; i < 32; ++i) {
            c += ((pk[i] & 0xFFFFu) >= tau) ? 1u : 0u;
            c += ((pk[i] >> 16) >= tau) ? 1u : 0u;
        }
#pragma unroll
        for (int s = 32; s > 0; s >>= 1) c += __shfl_xor(c, s, 64);
        if (lane == 0) wsum[wid] = c;
        __syncthreads();
        unsigned tot = wsum[0] + wsum[1] + wsum[2] + wsum[3];
        __syncthreads();
        return tot;
    };

    // tau = max t s.t. count(>=t) >= 48 ; early-accept when 48<=c<=CANDCAP
    unsigned lo = 0, hi = 0xFFFFu;
    for (int it = 0; it < 16 && lo < hi; ++it) {
        unsigned mid = (lo + hi + 1) >> 1;
        unsigned c = countGE(mid);
        if (c >= 48u) {
            lo = mid;
            if (c <= (unsigned)CANDCAP) break;
        } else {
            hi = mid - 1;
        }
    }
    const unsigned tau = lo;

    if (tid == 0) scount = 0;
    __syncthreads();
    const int gtok = tok0 + t;
#pragma unroll
    for (int i = 0; i < 32; ++i) {
        unsigned l16 = pk[i] & 0xFFFFu, h16 = pk[i] >> 16;
        if (l16 >= tau) {
            unsigned p = atomicAdd(&scount, 1u);
            if (p < CANDCAP) cand[(size_t)gtok * CANDCAP + p] = tid * 64 + i * 2;
        }
        if (h16 >= tau) {
            unsigned p = atomicAdd(&scount, 1u);
            if (p < CANDCAP) cand[(size_t)gtok * CANDCAP + p] = tid * 64 + i * 2 + 1;
        }
    }
    __syncthreads();
    if (tid == 0) ncand[gtok] = (int)(scount < (unsigned)CANDCAP ? scount : (unsigned)CANDCAP);
}

// ---------------- f64 rescore -> exact top-32 -> decode, fused ----------------
__global__ __launch_bounds__(256) void rescore_decode(
    const float* __restrict__ x, const float* __restrict__ peb,
    const float* __restrict__ WTT, const float* __restrict__ bias1,
    const int* __restrict__ cand, const int* __restrict__ ncand,
    const float* __restrict__ W, const float* __restrict__ b2,
    float* __restrict__ out)
{
    const int t = blockIdx.x;
    const int tid = threadIdx.x;
    __shared__ double xcs[INPUT];
    __shared__ double cval[CANDCAP];
    __shared__ int cidx[CANDCAP];
    __shared__ float sel_v[KSEL];
    __shared__ int sel_i[KSEL];

    const int nc = ncand[t];

#pragma unroll
    for (int i = 0; i < 4; ++i) {
        int j = tid + i * 256;
        xcs[j] = (double)x[(size_t)t * INPUT + j] - (double)peb[j];
    }
    if (tid < nc) cidx[tid] = cand[(size_t)t * CANDCAP + tid];
    __syncthreads();

    const int wid = tid >> 6, lane = tid & 63;
    for (int j = wid; j < nc; j += 4) {
        const int h = cidx[j];
        const float* wrow = WTT + (size_t)h * INPUT;
        double s = 0.0;
#pragma unroll
        for (int st = 0; st < 16; ++st)
            s += (double)wrow[lane + st * 64] * xcs[lane + st * 64];
#pragma unroll
        for (int off = 32; off > 0; off >>= 1)
            s += __shfl_xor(s, off, 64);
        if (lane == 0) cval[j] = s + (double)bias1[h];
    }
    __syncthreads();

    if (tid < nc) {
        const double v = cval[tid];
        const int h = cidx[tid];
        int rank = 0;
        for (int j = 0; j < nc; ++j) {
            double vj = cval[j];
            if (vj > v || (vj == v && cidx[j] < h)) ++rank;
        }
        if (rank < KSEL) {
            sel_v[rank] = (float)v;
            sel_i[rank] = h;
        }
    }
    __syncthreads();

    const int c = tid * 4;
    float4 acc = *(const float4*)&b2[c];
#pragma unroll 8
    for (int j = 0; j < KSEL; ++j) {
        const float4 wv = *(const float4*)&W[(size_t)sel_i[j] * INPUT + c];
        const float s = sel_v[j];
        acc.x += s * wv.x; acc.y += s * wv.y; acc.z += s * wv.z; acc.w += s * wv.w;
    }
    *(float4*)&out[(size_t)t * INPUT + c] = acc;
}

extern "C" void kernel_launch(void* const* d_in, const int* in_sizes, int n_in,
                              void* d_out, int out_size, void* d_ws, size_t ws_size,
                              hipStream_t stream) {
    const float* x   = (const float*)d_in[0];
    const float* peb = (const float*)d_in[1];
    const float* W   = (const float*)d_in[2];
    const float* WT  = (const float*)d_in[3];
    const float* b1  = (const float*)d_in[4];
    const float* b2  = (const float*)d_in[5];
    float* out = (float*)d_out;

    // ws: cand | ncand | WTT(f32) | Abf(bf16) | Btb(bf16) | pre chunk (bf16)
    char* p = (char*)d_ws;
    int*   candb = (int*)p;    p += (size_t)TOKENS * CANDCAP * 4;
    int*   ncb   = (int*)p;    p += (size_t)TOKENS * 4;
    float* WTT   = (float*)p;  p += (size_t)HIDDEN * INPUT * 4;
    short* Abf   = (short*)p;  p += (size_t)TOKENS * INPUT * 2;
    short* Btb   = (short*)p;  p += (size_t)HIDDEN * INPUT * 2;
    short* pre   = (short*)p;

    size_t used = (size_t)(p - (char*)d_ws);
    size_t avail = ws_size > used ? ws_size - used : 0;
    long cap = (long)(avail / ((size_t)HIDDEN * 2));
    cap = (cap / BM) * BM;
    if (cap > TOKENS) cap = TOKENS;
    if (cap < BM) cap = BM;

    conv_x<<<dim3(TOKENS * INPUT / (256 * 8)), dim3(256), 0, stream>>>(x, peb, Abf);
    transp<<<dim3(HIDDEN / 64, INPUT / 64), dim3(256), 0, stream>>>(WT, WTT);
    conv_bt<<<dim3((unsigned)((size_t)HIDDEN * INPUT / (256 * 8))), dim3(256), 0, stream>>>(WTT, Btb);

    for (int tok0 = 0; tok0 < TOKENS; tok0 += (int)cap) {
        int M = TOKENS - tok0;
        if (M > cap) M = (int)cap;
        gemm_bf16<<<dim3(HIDDEN / BN, M / BM), dim3(256), 0, stream>>>(Abf, Btb, b1, pre, tok0);
        topcand2<<<dim3(M), dim3(256), 0, stream>>>(pre, candb, ncb, tok0);
    }

    rescore_decode<<<dim3(TOKENS), dim3(256), 0, stream>>>(
        x, peb, WTT, b1, candb, ncb, W, b2, out);
}

// Round 5
// 938.475 us; speedup vs baseline: 5.1623x; 1.0203x over previous
//
#include <hip/hip_runtime.h>
#include <hip/hip_bf16.h>

#define TOKENS 8192
#define INPUT  1024
#define HIDDEN 16384
#define KSEL   32
#define CANDCAP 96
#define BM 128
#define BN 128

typedef __attribute__((ext_vector_type(8))) short bf16x8;
typedef __attribute__((ext_vector_type(4))) float f32x4;

#define GLOAD_LDS16(g, l) __builtin_amdgcn_global_load_lds(              \
    (const __attribute__((address_space(1))) void*)(const void*)(g),     \
    (__attribute__((address_space(3))) void*)(void*)(l), 16, 0, 0)

__device__ inline short f2bf(float f) {
    unsigned u = __float_as_uint(f);
    u += 0x7FFFu + ((u >> 16) & 1u);   // RNE
    return (short)(u >> 16);
}

// ---------------- Abf = bf16(x - peb) ----------------
__global__ __launch_bounds__(256) void conv_x(
    const float* __restrict__ x, const float* __restrict__ peb,
    short* __restrict__ Abf)
{
    const int g = (blockIdx.x * 256 + threadIdx.x) * 8;
    const int col = g & (INPUT - 1);
    float4 v0 = *(const float4*)&x[g];
    float4 v1 = *(const float4*)&x[g + 4];
    float4 p0 = *(const float4*)&peb[col];
    float4 p1 = *(const float4*)&peb[col + 4];
    short o[8] = {f2bf(v0.x - p0.x), f2bf(v0.y - p0.y), f2bf(v0.z - p0.z), f2bf(v0.w - p0.w),
                  f2bf(v1.x - p1.x), f2bf(v1.y - p1.y), f2bf(v1.z - p1.z), f2bf(v1.w - p1.w)};
    *(bf16x8*)&Abf[g] = *(bf16x8*)o;
}

// ---------------- Transpose WT -> WTT[HIDDEN][INPUT] (fp32, for rescore) ----------------
__global__ __launch_bounds__(256) void transp(
    const float* __restrict__ WT, float* __restrict__ WTT)
{
    __shared__ float tl[64][65];
    const int bx = blockIdx.x, by = blockIdx.y;
    const int tid = threadIdx.x;
    const int r0 = tid >> 6, c = tid & 63;
#pragma unroll
    for (int i = 0; i < 16; ++i) {
        int r = i * 4 + r0;
        tl[r][c] = WT[(size_t)(by * 64 + r) * HIDDEN + bx * 64 + c];
    }
    __syncthreads();
#pragma unroll
    for (int i = 0; i < 16; ++i) {
        int a = i * 4 + r0;
        WTT[(size_t)(bx * 64 + a) * INPUT + by * 64 + c] = tl[c][a];
    }
}

// ---------------- Bt = bf16(WTT) elementwise ----------------
__global__ __launch_bounds__(256) void conv_bt(
    const float* __restrict__ WTT, short* __restrict__ Bt)
{
    const int g = (blockIdx.x * 256 + threadIdx.x) * 8;
    float4 v0 = *(const float4*)&WTT[g];
    float4 v1 = *(const float4*)&WTT[g + 4];
    short o[8] = {f2bf(v0.x), f2bf(v0.y), f2bf(v0.z), f2bf(v0.w),
                  f2bf(v1.x), f2bf(v1.y), f2bf(v1.z), f2bf(v1.w)};
    *(bf16x8*)&Bt[g] = *(bf16x8*)o;
}

// ---------------- bf16 MFMA GEMM: pre_bf16 = bf16(Abf @ Bt^T + b1) ----------------
__global__ __launch_bounds__(256) void gemm_bf16(
    const short* __restrict__ A,   // [TOKENS][INPUT] bf16
    const short* __restrict__ Bt,  // [HIDDEN][INPUT] bf16
    const float* __restrict__ bias1,
    short* __restrict__ pre,       // [chunkM][HIDDEN] bf16
    int tok0)
{
    __shared__ short As[BM * 32];
    __shared__ short Bs[BN * 32];
    const int tid = threadIdx.x;
    const int bn = blockIdx.x, bm = blockIdx.y;
    const int row0 = tok0 + bm * BM;
    const int col0 = bn * BN;
    const int lane = tid & 63, w = tid >> 6;
    const int wr = w >> 1, wc = w & 1;

    f32x4 acc[4][4];
#pragma unroll
    for (int m = 0; m < 4; ++m)
#pragma unroll
        for (int n = 0; n < 4; ++n) acc[m][n] = (f32x4){0.f, 0.f, 0.f, 0.f};

    const int rbase = lane & 15;
    const int koff = (lane >> 4) * 8;

    for (int kt = 0; kt < INPUT / 32; ++kt) {
        __syncthreads();
#pragma unroll
        for (int i = 0; i < 2; ++i) {
            int idx = i * 256 + tid;
            int r = idx >> 2, seg = idx & 3;
            GLOAD_LDS16(&A[(size_t)(row0 + r) * INPUT + kt * 32 + seg * 8], &As[idx * 8]);
            GLOAD_LDS16(&Bt[(size_t)(col0 + r) * INPUT + kt * 32 + seg * 8], &Bs[idx * 8]);
        }
        __syncthreads();

        bf16x8 af[4], bfr[4];
#pragma unroll
        for (int m = 0; m < 4; ++m)
            af[m] = *(const bf16x8*)&As[(wr * 64 + m * 16 + rbase) * 32 + koff];
#pragma unroll
        for (int n = 0; n < 4; ++n)
            bfr[n] = *(const bf16x8*)&Bs[(wc * 64 + n * 16 + rbase) * 32 + koff];
#pragma unroll
        for (int m = 0; m < 4; ++m)
#pragma unroll
            for (int n = 0; n < 4; ++n)
                acc[m][n] = __builtin_amdgcn_mfma_f32_16x16x32_bf16(af[m], bfr[n], acc[m][n], 0, 0, 0);
    }

#pragma unroll
    for (int n = 0; n < 4; ++n) {
        const int col = col0 + wc * 64 + n * 16 + (lane & 15);
        const float bb = bias1[col];
#pragma unroll
        for (int m = 0; m < 4; ++m) {
#pragma unroll
            for (int r = 0; r < 4; ++r) {
                int row = bm * BM + wr * 64 + m * 16 + (lane >> 4) * 4 + r;
                pre[(size_t)row * HIDDEN + col] = f2bf(acc[m][n][r] + bb);
            }
        }
    }
}

// ---------------- Candidate select: tau binary search, accept window [40,48] ----------------
__global__ __launch_bounds__(256) void topcand2(
    const short* __restrict__ pre, // [chunkM][HIDDEN] bf16
    int* __restrict__ cand,        // [TOKENS][CANDCAP]
    int* __restrict__ ncand,       // [TOKENS]
    int tok0)
{
    const int tid = threadIdx.x;
    const int t = blockIdx.x;
    const unsigned short* row = (const unsigned short*)(pre + (size_t)t * HIDDEN);

    unsigned pk[32];
#pragma unroll
    for (int i = 0; i < 8; ++i) {
        uint4 raw = *(const uint4*)&row[(size_t)tid * 64 + i * 8];
        unsigned rr[4] = {raw.x, raw.y, raw.z, raw.w};
#pragma unroll
        for (int j = 0; j < 4; ++j) {
            unsigned lo16 = rr[j] & 0xFFFFu, hi16 = rr[j] >> 16;
            lo16 ^= (((lo16 >> 15) * 0xFFFFu) | 0x8000u);
            hi16 ^= (((hi16 >> 15) * 0xFFFFu) | 0x8000u);
            pk[i * 4 + j] = lo16 | (hi16 << 16);
        }
    }

    __shared__ unsigned wsum[4];
    __shared__ unsigned scount;
    const int lane = tid & 63, wid = tid >> 6;

    auto countGE = [&](unsigned tau) -> unsigned {
        unsigned c = 0;
#pragma unroll
        for (int i = 0; i < 32; ++i) {
            c += ((pk[i] & 0xFFFFu) >= tau) ? 1u : 0u;
            c += ((pk[i] >> 16) >= tau) ? 1u : 0u;
        }
#pragma unroll
        for (int s = 32; s > 0; s >>= 1) c += __shfl_xor(c, s, 64);
        if (lane == 0) wsum[wid] = c;
        __syncthreads();
        unsigned tot = wsum[0] + wsum[1] + wsum[2] + wsum[3];
        __syncthreads();
        return tot;
    };

    // tau = max t s.t. count(>=t) >= 40 ; early-accept when 40<=c<=48
    unsigned lo = 0, hi = 0xFFFFu;
    for (int it = 0; it < 17 && lo < hi; ++it) {
        unsigned mid = (lo + hi + 1) >> 1;
        unsigned c = countGE(mid);
        if (c >= 40u) {
            lo = mid;
            if (c <= 48u) break;
        } else {
            hi = mid - 1;
        }
    }
    const unsigned tau = lo;

    if (tid == 0) scount = 0;
    __syncthreads();
    const int gtok = tok0 + t;
#pragma unroll
    for (int i = 0; i < 32; ++i) {
        unsigned l16 = pk[i] & 0xFFFFu, h16 = pk[i] >> 16;
        if (l16 >= tau) {
            unsigned p = atomicAdd(&scount, 1u);
            if (p < CANDCAP) cand[(size_t)gtok * CANDCAP + p] = tid * 64 + i * 2;
        }
        if (h16 >= tau) {
            unsigned p = atomicAdd(&scount, 1u);
            if (p < CANDCAP) cand[(size_t)gtok * CANDCAP + p] = tid * 64 + i * 2 + 1;
        }
    }
    __syncthreads();
    if (tid == 0) ncand[gtok] = (int)(scount < (unsigned)CANDCAP ? scount : (unsigned)CANDCAP);
}

// ---------------- f64 rescore -> exact top-32 -> decode, fused ----------------
__global__ __launch_bounds__(256) void rescore_decode(
    const float* __restrict__ x, const float* __restrict__ peb,
    const float* __restrict__ WTT, const float* __restrict__ bias1,
    const int* __restrict__ cand, const int* __restrict__ ncand,
    const float* __restrict__ W, const float* __restrict__ b2,
    float* __restrict__ out)
{
    const int t = blockIdx.x;
    const int tid = threadIdx.x;
    __shared__ double xcs[INPUT];
    __shared__ double cval[CANDCAP];
    __shared__ int cidx[CANDCAP];
    __shared__ float sel_v[KSEL];
    __shared__ int sel_i[KSEL];

    const int nc = ncand[t];

#pragma unroll
    for (int i = 0; i < 4; ++i) {
        int j = tid + i * 256;
        xcs[j] = (double)x[(size_t)t * INPUT + j] - (double)peb[j];
    }
    if (tid < nc) cidx[tid] = cand[(size_t)t * CANDCAP + tid];
    __syncthreads();

    const int wid = tid >> 6, lane = tid & 63;
    // 2 rows per wave-iteration -> 32 outstanding loads/wave for latency hiding
    for (int j0 = wid * 2; j0 < nc; j0 += 8) {
        const int j1 = j0 + 1;
        const int h0 = cidx[j0];
        const int h1 = (j1 < nc) ? cidx[j1] : h0;
        const float* w0 = WTT + (size_t)h0 * INPUT;
        const float* w1 = WTT + (size_t)h1 * INPUT;
        double s0 = 0.0, s1 = 0.0;
#pragma unroll
        for (int st = 0; st < 16; ++st) {
            const double xv = xcs[lane + st * 64];
            s0 += (double)w0[lane + st * 64] * xv;
            s1 += (double)w1[lane + st * 64] * xv;
        }
#pragma unroll
        for (int off = 32; off > 0; off >>= 1) {
            s0 += __shfl_xor(s0, off, 64);
            s1 += __shfl_xor(s1, off, 64);
        }
        if (lane == 0) {
            cval[j0] = s0 + (double)bias1[h0];
            if (j1 < nc) cval[j1] = s1 + (double)bias1[h1];
        }
    }
    __syncthreads();

    if (tid < nc) {
        const double v = cval[tid];
        const int h = cidx[tid];
        int rank = 0;
        for (int j = 0; j < nc; ++j) {
            double vj = cval[j];
            if (vj > v || (vj == v && cidx[j] < h)) ++rank;
        }
        if (rank < KSEL) {
            sel_v[rank] = (float)v;
            sel_i[rank] = h;
        }
    }
    __syncthreads();

    const int c = tid * 4;
    float4 acc = *(const float4*)&b2[c];
#pragma unroll 8
    for (int j = 0; j < KSEL; ++j) {
        const float4 wv = *(const float4*)&W[(size_t)sel_i[j] * INPUT + c];
        const float s = sel_v[j];
        acc.x += s * wv.x; acc.y += s * wv.y; acc.z += s * wv.z; acc.w += s * wv.w;
    }
    *(float4*)&out[(size_t)t * INPUT + c] = acc;
}

extern "C" void kernel_launch(void* const* d_in, const int* in_sizes, int n_in,
                              void* d_out, int out_size, void* d_ws, size_t ws_size,
                              hipStream_t stream) {
    const float* x   = (const float*)d_in[0];
    const float* peb = (const float*)d_in[1];
    const float* W   = (const float*)d_in[2];
    const float* WT  = (const float*)d_in[3];
    const float* b1  = (const float*)d_in[4];
    const float* b2  = (const float*)d_in[5];
    float* out = (float*)d_out;

    // ws: cand | ncand | WTT(f32) | Abf(bf16) | Btb(bf16) | pre chunk (bf16)
    char* p = (char*)d_ws;
    int*   candb = (int*)p;    p += (size_t)TOKENS * CANDCAP * 4;
    int*   ncb   = (int*)p;    p += (size_t)TOKENS * 4;
    float* WTT   = (float*)p;  p += (size_t)HIDDEN * INPUT * 4;
    short* Abf   = (short*)p;  p += (size_t)TOKENS * INPUT * 2;
    short* Btb   = (short*)p;  p += (size_t)HIDDEN * INPUT * 2;
    short* pre   = (short*)p;

    size_t used = (size_t)(p - (char*)d_ws);
    size_t avail = ws_size > used ? ws_size - used : 0;
    long cap = (long)(avail / ((size_t)HIDDEN * 2));
    cap = (cap / BM) * BM;
    if (cap > TOKENS) cap = TOKENS;
    if (cap < BM) cap = BM;

    conv_x<<<dim3(TOKENS * INPUT / (256 * 8)), dim3(256), 0, stream>>>(x, peb, Abf);
    transp<<<dim3(HIDDEN / 64, INPUT / 64), dim3(256), 0, stream>>>(WT, WTT);
    conv_bt<<<dim3((unsigned)((size_t)HIDDEN * INPUT / (256 * 8))), dim3(256), 0, stream>>>(WTT, Btb);

    for (int tok0 = 0; tok0 < TOKENS; tok0 += (int)cap) {
        int M = TOKENS - tok0;
        if (M > cap) M = (int)cap;
        gemm_bf16<<<dim3(HIDDEN / BN, M / BM), dim3(256), 0, stream>>>(Abf, Btb, b1, pre, tok0);
        topcand2<<<dim3(M), dim3(256), 0, stream>>>(pre, candb, ncb, tok0);
    }

    rescore_decode<<<dim3(TOKENS), dim3(256), 0, stream>>>(
        x, peb, WTT, b1, candb, ncb, W, b2, out);
}

// Round 6
// 851.316 us; speedup vs baseline: 5.6908x; 1.1024x over previous
//
#include <hip/hip_runtime.h>
#include <hip/hip_fp16.h>

#define TOKENS 8192
#define INPUT  1024
#define HIDDEN 16384
#define KSEL   32
#define CANDCAP 96
#define TWO_E  0.012f
#define BM 128
#define BN 128

typedef __attribute__((ext_vector_type(8))) short bf16x8;
typedef __attribute__((ext_vector_type(4))) float f32x4;

#define GLOAD_LDS16(g, l) __builtin_amdgcn_global_load_lds(              \
    (const __attribute__((address_space(1))) void*)(const void*)(g),     \
    (__attribute__((address_space(3))) void*)(void*)(l), 16, 0, 0)

__device__ inline short f2bf(float f) {
    unsigned u = __float_as_uint(f);
    u += 0x7FFFu + ((u >> 16) & 1u);   // RNE
    return (short)(u >> 16);
}

__device__ inline float keyToF(unsigned k) {
    unsigned o = (k & 0x8000u) ? (k ^ 0x8000u) : (~k & 0xFFFFu);
    return __half2float(__ushort_as_half((unsigned short)o));
}

// ---------------- Abf = bf16(x - peb) ----------------
__global__ __launch_bounds__(256) void conv_x(
    const float* __restrict__ x, const float* __restrict__ peb,
    short* __restrict__ Abf)
{
    const int g = (blockIdx.x * 256 + threadIdx.x) * 8;
    const int col = g & (INPUT - 1);
    float4 v0 = *(const float4*)&x[g];
    float4 v1 = *(const float4*)&x[g + 4];
    float4 p0 = *(const float4*)&peb[col];
    float4 p1 = *(const float4*)&peb[col + 4];
    short o[8] = {f2bf(v0.x - p0.x), f2bf(v0.y - p0.y), f2bf(v0.z - p0.z), f2bf(v0.w - p0.w),
                  f2bf(v1.x - p1.x), f2bf(v1.y - p1.y), f2bf(v1.z - p1.z), f2bf(v1.w - p1.w)};
    *(bf16x8*)&Abf[g] = *(bf16x8*)o;
}

// ---------------- Transpose WT -> WTT[HIDDEN][INPUT] fp32 AND Btb bf16 ----------------
__global__ __launch_bounds__(256) void transp2(
    const float* __restrict__ WT, float* __restrict__ WTT, short* __restrict__ Btb)
{
    __shared__ float tl[64][65];
    const int bx = blockIdx.x, by = blockIdx.y;
    const int tid = threadIdx.x;
    const int r0 = tid >> 6, c = tid & 63;
#pragma unroll
    for (int i = 0; i < 16; ++i) {
        int r = i * 4 + r0;
        tl[r][c] = WT[(size_t)(by * 64 + r) * HIDDEN + bx * 64 + c];
    }
    __syncthreads();
#pragma unroll
    for (int i = 0; i < 16; ++i) {
        int a = i * 4 + r0;
        float v = tl[c][a];
        size_t o = (size_t)(bx * 64 + a) * INPUT + by * 64 + c;
        WTT[o] = v;
        Btb[o] = f2bf(v);
    }
}

// ---------------- Whf = fp16(W) ----------------
__global__ __launch_bounds__(256) void conv_whf(
    const float* __restrict__ W, unsigned short* __restrict__ Whf)
{
    const size_t g = ((size_t)blockIdx.x * 256 + threadIdx.x) * 8;
    float4 v0 = *(const float4*)&W[g];
    float4 v1 = *(const float4*)&W[g + 4];
    unsigned short o[8] = {
        __half_as_ushort(__float2half(v0.x)), __half_as_ushort(__float2half(v0.y)),
        __half_as_ushort(__float2half(v0.z)), __half_as_ushort(__float2half(v0.w)),
        __half_as_ushort(__float2half(v1.x)), __half_as_ushort(__float2half(v1.y)),
        __half_as_ushort(__float2half(v1.z)), __half_as_ushort(__float2half(v1.w))};
    *(uint4*)&Whf[g] = *(uint4*)o;
}

// ---------------- bf16 MFMA GEMM: pre16 = fp16(Abf @ Btb^T + b1) ----------------
__global__ __launch_bounds__(256) void gemm_bf16(
    const short* __restrict__ A,   // [TOKENS][INPUT] bf16
    const short* __restrict__ Bt,  // [HIDDEN][INPUT] bf16
    const float* __restrict__ bias1,
    unsigned short* __restrict__ pre16, // [chunkM][HIDDEN] fp16
    int tok0)
{
    __shared__ short As[BM * 32];
    __shared__ short Bs[BN * 32];
    const int tid = threadIdx.x;
    const int bn = blockIdx.x, bm = blockIdx.y;
    const int row0 = tok0 + bm * BM;
    const int col0 = bn * BN;
    const int lane = tid & 63, w = tid >> 6;
    const int wr = w >> 1, wc = w & 1;

    f32x4 acc[4][4];
#pragma unroll
    for (int m = 0; m < 4; ++m)
#pragma unroll
        for (int n = 0; n < 4; ++n) acc[m][n] = (f32x4){0.f, 0.f, 0.f, 0.f};

    const int rbase = lane & 15;
    const int koff = (lane >> 4) * 8;

    for (int kt = 0; kt < INPUT / 32; ++kt) {
        __syncthreads();
#pragma unroll
        for (int i = 0; i < 2; ++i) {
            int idx = i * 256 + tid;
            int r = idx >> 2, seg = idx & 3;
            GLOAD_LDS16(&A[(size_t)(row0 + r) * INPUT + kt * 32 + seg * 8], &As[idx * 8]);
            GLOAD_LDS16(&Bt[(size_t)(col0 + r) * INPUT + kt * 32 + seg * 8], &Bs[idx * 8]);
        }
        __syncthreads();

        bf16x8 af[4], bfr[4];
#pragma unroll
        for (int m = 0; m < 4; ++m)
            af[m] = *(const bf16x8*)&As[(wr * 64 + m * 16 + rbase) * 32 + koff];
#pragma unroll
        for (int n = 0; n < 4; ++n)
            bfr[n] = *(const bf16x8*)&Bs[(wc * 64 + n * 16 + rbase) * 32 + koff];
#pragma unroll
        for (int m = 0; m < 4; ++m)
#pragma unroll
            for (int n = 0; n < 4; ++n)
                acc[m][n] = __builtin_amdgcn_mfma_f32_16x16x32_bf16(af[m], bfr[n], acc[m][n], 0, 0, 0);
    }

#pragma unroll
    for (int n = 0; n < 4; ++n) {
        const int col = col0 + wc * 64 + n * 16 + (lane & 15);
        const float bb = bias1[col];
#pragma unroll
        for (int m = 0; m < 4; ++m) {
#pragma unroll
            for (int r = 0; r < 4; ++r) {
                int row = bm * BM + wr * 64 + m * 16 + (lane >> 4) * 4 + r;
                pre16[(size_t)row * HIDDEN + col] =
                    __half_as_ushort(__float2half(acc[m][n][r] + bb));
            }
        }
    }
}

// ---------------- Candidate select on fp16 keys; widened threshold; deterministic ----------------
__global__ __launch_bounds__(256) void topcand3(
    const unsigned short* __restrict__ pre16, // [chunkM][HIDDEN] fp16
    int* __restrict__ cand,  // [TOKENS][CANDCAP]
    float* __restrict__ scr, // [TOKENS][CANDCAP] screen values
    int* __restrict__ ncand, // [TOKENS]
    int tok0)
{
    const int tid = threadIdx.x;
    const int t = blockIdx.x;
    const unsigned short* row = pre16 + (size_t)t * HIDDEN;

    unsigned pk[32];
#pragma unroll
    for (int i = 0; i < 8; ++i) {
        uint4 raw = *(const uint4*)&row[(size_t)tid * 64 + i * 8];
        unsigned rr[4] = {raw.x, raw.y, raw.z, raw.w};
#pragma unroll
        for (int j = 0; j < 4; ++j) {
            unsigned lo16 = rr[j] & 0xFFFFu, hi16 = rr[j] >> 16;
            lo16 ^= (((lo16 >> 15) * 0xFFFFu) | 0x8000u);
            hi16 ^= (((hi16 >> 15) * 0xFFFFu) | 0x8000u);
            pk[i * 4 + j] = lo16 | (hi16 << 16);
        }
    }

    __shared__ unsigned wsum[4];
    const int lane = tid & 63, wid = tid >> 6;

    auto countGE = [&](unsigned tau) -> unsigned {
        unsigned c = 0;
#pragma unroll
        for (int i = 0; i < 32; ++i) {
            c += ((pk[i] & 0xFFFFu) >= tau) ? 1u : 0u;
            c += ((pk[i] >> 16) >= tau) ? 1u : 0u;
        }
#pragma unroll
        for (int s = 32; s > 0; s >>= 1) c += __shfl_xor(c, s, 64);
        if (lane == 0) wsum[wid] = c;
        __syncthreads();
        unsigned tot = wsum[0] + wsum[1] + wsum[2] + wsum[3];
        __syncthreads();
        return tot;
    };

    // tau40 = max t s.t. count(>=t) >= 40; early accept [40,48]
    unsigned lo = 0, hi = 0xFFFFu;
    for (int it = 0; it < 17 && lo < hi; ++it) {
        unsigned mid = (lo + hi + 1) >> 1;
        unsigned c = countGE(mid);
        if (c >= 40u) { lo = mid; if (c <= 48u) break; }
        else hi = mid - 1;
    }
    // widen by 2E (+fp16 slack) in value domain: guarantees coverage >= s32 - 2E
    float v40 = keyToF(lo);
    float vthr = v40 - (TWO_E + 0.002f);
    unsigned kthr = (unsigned)__half_as_ushort(__float2half(vthr));
    kthr ^= (((kthr >> 15) * 0xFFFFu) | 0x8000u);

    // deterministic prefix compaction
    __shared__ unsigned short cnts[256];
    unsigned mycnt = 0;
#pragma unroll
    for (int i = 0; i < 32; ++i) {
        mycnt += ((pk[i] & 0xFFFFu) >= kthr) ? 1u : 0u;
        mycnt += ((pk[i] >> 16) >= kthr) ? 1u : 0u;
    }
    cnts[tid] = (unsigned short)mycnt;
    __syncthreads();
    unsigned base = 0, tot = 0;
    for (int k = 0; k < 256; ++k) {
        unsigned ck = cnts[k];
        if (k < tid) base += ck;
        tot += ck;
    }
    const int gtok = tok0 + t;
    unsigned pos = base;
#pragma unroll
    for (int i = 0; i < 32; ++i) {
        unsigned l16 = pk[i] & 0xFFFFu, h16 = pk[i] >> 16;
        if (l16 >= kthr) {
            if (pos < CANDCAP) {
                cand[(size_t)gtok * CANDCAP + pos] = tid * 64 + i * 2;
                scr[(size_t)gtok * CANDCAP + pos] = keyToF(l16);
            }
            ++pos;
        }
        if (h16 >= kthr) {
            if (pos < CANDCAP) {
                cand[(size_t)gtok * CANDCAP + pos] = tid * 64 + i * 2 + 1;
                scr[(size_t)gtok * CANDCAP + pos] = keyToF(h16);
            }
            ++pos;
        }
    }
    if (tid == 0) ncand[gtok] = (int)(tot < (unsigned)CANDCAP ? tot : (unsigned)CANDCAP);
}

// ---------------- Band f64 rescore -> exact selection -> fp16 decode, fused ----------------
__global__ __launch_bounds__(256) void rescore_band_decode(
    const float* __restrict__ x, const float* __restrict__ peb,
    const float* __restrict__ WTT, const float* __restrict__ bias1,
    const int* __restrict__ cand, const float* __restrict__ scr,
    const int* __restrict__ ncand,
    const unsigned short* __restrict__ Whf, const float* __restrict__ b2,
    float* __restrict__ out)
{
    const int t = blockIdx.x;
    const int tid = threadIdx.x;
    __shared__ double xcs[INPUT];
    __shared__ float sv[CANDCAP];
    __shared__ int   si[CANDCAP];
    __shared__ double bex[CANDCAP];
    __shared__ unsigned char flg[CANDCAP];
    __shared__ unsigned char self_[CANDCAP];
    __shared__ short bandlist[CANDCAP];
    __shared__ float s32s;
    __shared__ int bns, nins;
    __shared__ float sel_v[KSEL];
    __shared__ int sel_i[KSEL];

    const int nc0 = ncand[t];
    const int nc = nc0 < CANDCAP ? nc0 : CANDCAP;

#pragma unroll
    for (int i = 0; i < 4; ++i) {
        int j = tid + i * 256;
        xcs[j] = (double)x[(size_t)t * INPUT + j] - (double)peb[j];
    }
    if (tid < nc) {
        sv[tid] = scr[(size_t)t * CANDCAP + tid];
        si[tid] = cand[(size_t)t * CANDCAP + tid];
    }
    __syncthreads();

    // rank-31 screen value (total order: value desc, idx asc)
    if (tid < nc) {
        float v = sv[tid]; int h = si[tid];
        int r = 0;
        for (int k = 0; k < nc; ++k) {
            float vk = sv[k];
            if (vk > v || (vk == v && si[k] < h)) ++r;
        }
        if (r == 31) s32s = v;
    }
    __syncthreads();
    const float s32 = s32s;

    if (tid < nc) {
        float v = sv[tid];
        flg[tid] = (v > s32 + TWO_E) ? 2 : ((v >= s32 - TWO_E) ? 1 : 0);
    }
    __syncthreads();
    if (tid == 0) {
        int bn = 0, nin = 0;
        for (int k = 0; k < nc; ++k) {
            if (flg[k] == 1) bandlist[bn++] = (short)k;
            else if (flg[k] == 2) ++nin;
        }
        bns = bn; nins = nin;
    }
    __syncthreads();
    const int bn = bns, need = KSEL - nins;

    // f64 exact scoring of band members only
    const int wid = tid >> 6, lane = tid & 63;
    for (int j0 = wid * 2; j0 < bn; j0 += 8) {
        const int j1 = j0 + 1;
        const int c0 = bandlist[j0];
        const int c1 = (j1 < bn) ? bandlist[j1] : c0;
        const int h0 = si[c0], h1 = si[c1];
        const float* w0 = WTT + (size_t)h0 * INPUT;
        const float* w1 = WTT + (size_t)h1 * INPUT;
        double s0 = 0.0, s1 = 0.0;
#pragma unroll
        for (int st = 0; st < 16; ++st) {
            const double xv = xcs[lane + st * 64];
            s0 += (double)w0[lane + st * 64] * xv;
            s1 += (double)w1[lane + st * 64] * xv;
        }
#pragma unroll
        for (int off = 32; off > 0; off >>= 1) {
            s0 += __shfl_xor(s0, off, 64);
            s1 += __shfl_xor(s1, off, 64);
        }
        if (lane == 0) {
            bex[c0] = s0 + (double)bias1[h0];
            if (j1 < bn) bex[c1] = s1 + (double)bias1[h1];
        }
    }
    __syncthreads();

    // final selection: certain-in + top-need of band by (exact desc, idx asc)
    if (tid < nc) {
        int s = 0;
        if (flg[tid] == 2) s = 1;
        else if (flg[tid] == 1) {
            double v = bex[tid]; int h = si[tid];
            int r = 0;
            for (int k = 0; k < bn; ++k) {
                int ck = bandlist[k];
                double vk = bex[ck];
                if (vk > v || (vk == v && si[ck] < h)) ++r;
            }
            if (r < need) s = 1;
        }
        self_[tid] = (unsigned char)s;
    }
    __syncthreads();
    if (tid < nc && self_[tid]) {
        int pos = 0;
        for (int k = 0; k < tid; ++k) pos += self_[k];
        if (pos < KSEL) {
            sel_v[pos] = (flg[tid] == 2) ? sv[tid] : (float)bex[tid];
            sel_i[pos] = si[tid];
        }
    }
    __syncthreads();

    // decode with fp16 W gather
    const int c = tid * 4;
    float4 acc = *(const float4*)&b2[c];
#pragma unroll 8
    for (int j = 0; j < KSEL; ++j) {
        const int h = sel_i[j];
        uint2 raw = *(const uint2*)&Whf[(size_t)h * INPUT + c];
        const float s = sel_v[j];
        __half2 p0 = *(__half2*)&raw.x;
        __half2 p1 = *(__half2*)&raw.y;
        float2 f0 = __half22float2(p0);
        float2 f1 = __half22float2(p1);
        acc.x += s * f0.x; acc.y += s * f0.y; acc.z += s * f1.x; acc.w += s * f1.y;
    }
    *(float4*)&out[(size_t)t * INPUT + c] = acc;
}

extern "C" void kernel_launch(void* const* d_in, const int* in_sizes, int n_in,
                              void* d_out, int out_size, void* d_ws, size_t ws_size,
                              hipStream_t stream) {
    const float* x   = (const float*)d_in[0];
    const float* peb = (const float*)d_in[1];
    const float* W   = (const float*)d_in[2];
    const float* WT  = (const float*)d_in[3];
    const float* b1  = (const float*)d_in[4];
    const float* b2  = (const float*)d_in[5];
    float* out = (float*)d_out;

    // ws: cand | scr | ncand | WTT f32 | Abf bf16 | Btb bf16 | Whf fp16 | pre16 chunk
    char* p = (char*)d_ws;
    int*   candb = (int*)p;            p += (size_t)TOKENS * CANDCAP * 4;
    float* scrb  = (float*)p;          p += (size_t)TOKENS * CANDCAP * 4;
    int*   ncb   = (int*)p;            p += (size_t)TOKENS * 4;
    float* WTT   = (float*)p;          p += (size_t)HIDDEN * INPUT * 4;
    short* Abf   = (short*)p;          p += (size_t)TOKENS * INPUT * 2;
    short* Btb   = (short*)p;          p += (size_t)HIDDEN * INPUT * 2;
    unsigned short* Whf = (unsigned short*)p; p += (size_t)HIDDEN * INPUT * 2;
    unsigned short* pre16 = (unsigned short*)p;

    size_t used = (size_t)(p - (char*)d_ws);
    size_t avail = ws_size > used ? ws_size - used : 0;
    long cap = (long)(avail / ((size_t)HIDDEN * 2));
    cap = (cap / BM) * BM;
    if (cap > TOKENS) cap = TOKENS;
    if (cap < BM) cap = BM;

    conv_x<<<dim3(TOKENS * INPUT / (256 * 8)), dim3(256), 0, stream>>>(x, peb, Abf);
    transp2<<<dim3(HIDDEN / 64, INPUT / 64), dim3(256), 0, stream>>>(WT, WTT, Btb);
    conv_whf<<<dim3((unsigned)((size_t)HIDDEN * INPUT / (256 * 8))), dim3(256), 0, stream>>>(W, Whf);

    for (int tok0 = 0; tok0 < TOKENS; tok0 += (int)cap) {
        int M = TOKENS - tok0;
        if (M > cap) M = (int)cap;
        gemm_bf16<<<dim3(HIDDEN / BN, M / BM), dim3(256), 0, stream>>>(Abf, Btb, b1, pre16, tok0);
        topcand3<<<dim3(M), dim3(256), 0, stream>>>(pre16, candb, scrb, ncb, tok0);
    }

    rescore_band_decode<<<dim3(TOKENS), dim3(256), 0, stream>>>(
        x, peb, WTT, b1, candb, scrb, ncb, Whf, b2, out);
}